// Round 1
// baseline (540.461 us; speedup 1.0000x reference)
//
#include <hip/hip_runtime.h>
#include <math.h>

#define BB 8
#define MM 64
#define DD 256
#define NP 16384
#define EPSF 1e-7f
#define NEPS 1e-12f

// ws layout (float offsets)
#define OFF_AT   0u         // At   [B][D][M]  alpha * normalized c, transposed
#define OFF_VC   131072u    // vc   [B][M][D]
#define OFF_AV   262144u    // AV   [B][M][D]  assignment @ values (atomic accum)
#define OFF_AGG  393216u    // agg  [B][M][D]
#define OFF_ASUM 524288u    // asum [B][M]
#define OFF_ASNT 524800u    // asnT [B][N][M]  assignment transposed
#define OFF_WCT  8913408u   // Wc^T [D][D]
#define OFF_WVT  8978944u   // Wv^T [D][D]

// ---------------- K0: transpose Wc, Wv ----------------
__global__ __launch_bounds__(256) void k0_transpose(
    const float* __restrict__ Wc, const float* __restrict__ Wv,
    float* __restrict__ ws)
{
    __shared__ float tls[32][33];
    int which = blockIdx.z;
    const float* W = which ? Wv : Wc;
    float* Wt = ws + (which ? OFF_WVT : OFF_WCT);
    int j0 = blockIdx.x * 32, k0 = blockIdx.y * 32;
    int c = threadIdx.x & 31, r0 = threadIdx.x >> 5;
    #pragma unroll
    for (int rr = r0; rr < 32; rr += 8)
        tls[rr][c] = W[(size_t)(j0 + rr) * DD + k0 + c];
    __syncthreads();
    #pragma unroll
    for (int rr = r0; rr < 32; rr += 8)
        Wt[(size_t)(k0 + rr) * DD + j0 + c] = tls[c][rr];
}

// ---------------- K1: c / vc prep ----------------
// which=0: At[b][d][m] = alpha[m] * l2norm(silu((clusters+cb)@Wc^T+bc))
// which=1: vc[b][m][d] = silu((vclusters+vcb)@Wv^T+bv)
__global__ __launch_bounds__(256) void k1_prep(
    const float* __restrict__ clusters, const float* __restrict__ vclusters,
    const float* __restrict__ alpha, const float* __restrict__ cbias,
    const float* __restrict__ bc, const float* __restrict__ vcbias,
    const float* __restrict__ bvv, float* __restrict__ ws)
{
    __shared__ float s_in[16][256];
    __shared__ float wt_s[32][256];
    __shared__ float s_out[16][260];
    __shared__ float s_scale[16];

    int t = threadIdx.x;
    int mt = blockIdx.x, b = blockIdx.y, which = blockIdx.z;
    int m0 = mt * 16;
    const float* inp   = which ? vclusters : clusters;
    const float* ibias = which ? vcbias : cbias;
    const float* obias = which ? bvv : bc;
    const float* Wt = ws + (which ? OFF_WVT : OFF_WCT);

    #pragma unroll
    for (int i = 0; i < 4; i++) {
        int e = i * 1024 + t * 4;
        int r = e >> 8, c = e & 255;
        float4 a  = *(const float4*)&inp[((size_t)(b * MM + m0 + r)) * DD + c];
        float4 bb = *(const float4*)&ibias[(size_t)(m0 + r) * DD + c];
        a.x += bb.x; a.y += bb.y; a.z += bb.z; a.w += bb.w;
        *(float4*)&s_in[r][c] = a;
    }

    int tm = t >> 5, tt = t & 31;
    float acc[2][8];
    #pragma unroll
    for (int i = 0; i < 2; i++)
        #pragma unroll
        for (int q = 0; q < 8; q++) acc[i][q] = 0.f;

    for (int k0 = 0; k0 < DD; k0 += 32) {
        __syncthreads();
        #pragma unroll
        for (int i = 0; i < 8; i++) {
            int e = i * 1024 + t * 4;
            int kd = e >> 8, c = e & 255;
            *(float4*)&wt_s[kd][c] = *(const float4*)&Wt[(size_t)(k0 + kd) * DD + c];
        }
        __syncthreads();
        #pragma unroll
        for (int kd = 0; kd < 32; kd++) {
            float a0 = s_in[tm][k0 + kd];
            float a1 = s_in[tm + 8][k0 + kd];
            float4 b0 = *(const float4*)&wt_s[kd][tt * 4];
            float4 b1 = *(const float4*)&wt_s[kd][128 + tt * 4];
            float bq[8] = {b0.x, b0.y, b0.z, b0.w, b1.x, b1.y, b1.z, b1.w};
            #pragma unroll
            for (int q = 0; q < 8; q++) { acc[0][q] += a0 * bq[q]; acc[1][q] += a1 * bq[q]; }
        }
    }

    #pragma unroll
    for (int q = 0; q < 8; q++) {
        int col = (q < 4) ? (tt * 4 + q) : (128 + tt * 4 + (q - 4));
        float ob = obias[col];
        #pragma unroll
        for (int i = 0; i < 2; i++) {
            int r = tm + i * 8;
            float x = acc[i][q] + ob;
            float s = x / (1.f + __expf(-x));   // silu
            s_out[r][col] = s;
        }
    }
    __syncthreads();

    if (which == 0) {
        if (t < 16) {
            float ss = 0.f;
            for (int j = 0; j < 256; j++) { float v = s_out[t][j]; ss += v * v; }
            s_scale[t] = alpha[m0 + t] / fmaxf(sqrtf(ss), NEPS);
        }
        __syncthreads();
        float* At = ws + OFF_AT + (size_t)b * DD * MM + (size_t)t * MM + m0;
        #pragma unroll
        for (int i = 0; i < 16; i++) At[i] = s_out[i][t] * s_scale[i];
    } else {
        float* vc = ws + OFF_VC + (size_t)(b * MM + m0) * DD;
        #pragma unroll
        for (int i = 0; i < 16; i++) vc[(size_t)i * DD + t] = s_out[i][t];
    }
}

// ---------------- K3: sim + softmax + asnT + asum ----------------
__global__ __launch_bounds__(256) void k3_sim(
    const float* __restrict__ points, const float* __restrict__ beta,
    float* __restrict__ ws)
{
    __shared__ float Ps[32][256];
    __shared__ float Ast[32][72];
    __shared__ float pinv[256];
    __shared__ float red[8][256];   // aliased: psum (rows 0..3), max, sum, redA[32][64]

    int t = threadIdx.x;
    int n0 = blockIdx.x * 256, b = blockIdx.y;
    int tm = t >> 5, tt = t & 31;
    const float* At = ws + OFF_AT + (size_t)b * DD * MM;
    const float* pb = points + (size_t)b * DD * NP;

    float acc[8][8];
    #pragma unroll
    for (int i = 0; i < 8; i++)
        #pragma unroll
        for (int q = 0; q < 8; q++) acc[i][q] = 0.f;

    float4 sq = make_float4(0.f, 0.f, 0.f, 0.f);
    int cth = (t & 63) * 4;

    for (int k0 = 0; k0 < DD; k0 += 32) {
        __syncthreads();
        #pragma unroll
        for (int i = 0; i < 8; i++) {
            int kd = i * 4 + (t >> 6);
            float4 v = *(const float4*)&pb[(size_t)(k0 + kd) * NP + n0 + cth];
            sq.x += v.x * v.x; sq.y += v.y * v.y; sq.z += v.z * v.z; sq.w += v.w * v.w;
            *(float4*)&Ps[kd][cth] = v;
        }
        {
            int kd = t >> 3, me = (t & 7) * 8;
            *(float4*)&Ast[kd][me]     = *(const float4*)&At[(size_t)(k0 + kd) * MM + me];
            *(float4*)&Ast[kd][me + 4] = *(const float4*)&At[(size_t)(k0 + kd) * MM + me + 4];
        }
        __syncthreads();
        #pragma unroll
        for (int kd = 0; kd < 32; kd++) {
            float4 a0 = *(const float4*)&Ast[kd][tm * 8];
            float4 a1 = *(const float4*)&Ast[kd][tm * 8 + 4];
            float4 b0 = *(const float4*)&Ps[kd][tt * 4];
            float4 b1 = *(const float4*)&Ps[kd][128 + tt * 4];
            float av[8] = {a0.x, a0.y, a0.z, a0.w, a1.x, a1.y, a1.z, a1.w};
            float bq[8] = {b0.x, b0.y, b0.z, b0.w, b1.x, b1.y, b1.z, b1.w};
            #pragma unroll
            for (int i = 0; i < 8; i++)
                #pragma unroll
                for (int q = 0; q < 8; q++) acc[i][q] += av[i] * bq[q];
        }
    }

    // column sumsq reduce -> pinv
    __syncthreads();
    *(float4*)&red[t >> 6][cth] = sq;
    __syncthreads();
    {
        float s = red[0][t] + red[1][t] + red[2][t] + red[3][t];
        pinv[t] = 1.f / fmaxf(sqrtf(s), NEPS);
    }
    __syncthreads();

    float sbet[8], pin[8];
    #pragma unroll
    for (int i = 0; i < 8; i++) sbet[i] = beta[tm * 8 + i];
    #pragma unroll
    for (int q = 0; q < 8; q++) {
        int col = (q < 4) ? (tt * 4 + q) : (128 + tt * 4 + (q - 4));
        pin[q] = pinv[col];
    }

    // v = acc*pinv + beta; partial max over our 8 m's
    float pmax[8];
    #pragma unroll
    for (int q = 0; q < 8; q++) {
        float mx = -1e30f;
        #pragma unroll
        for (int i = 0; i < 8; i++) {
            acc[i][q] = acc[i][q] * pin[q] + sbet[i];
            mx = fmaxf(mx, acc[i][q]);
        }
        pmax[q] = mx;
    }
    *(float4*)&red[tm][tt * 4]       = make_float4(pmax[0], pmax[1], pmax[2], pmax[3]);
    *(float4*)&red[tm][128 + tt * 4] = make_float4(pmax[4], pmax[5], pmax[6], pmax[7]);
    __syncthreads();
    float cmax[8];
    #pragma unroll
    for (int q = 0; q < 8; q++) cmax[q] = -1e30f;
    #pragma unroll
    for (int tr = 0; tr < 8; tr++) {
        float4 r0 = *(const float4*)&red[tr][tt * 4];
        float4 r1 = *(const float4*)&red[tr][128 + tt * 4];
        cmax[0] = fmaxf(cmax[0], r0.x); cmax[1] = fmaxf(cmax[1], r0.y);
        cmax[2] = fmaxf(cmax[2], r0.z); cmax[3] = fmaxf(cmax[3], r0.w);
        cmax[4] = fmaxf(cmax[4], r1.x); cmax[5] = fmaxf(cmax[5], r1.y);
        cmax[6] = fmaxf(cmax[6], r1.z); cmax[7] = fmaxf(cmax[7], r1.w);
    }
    __syncthreads();
    float ps[8];
    #pragma unroll
    for (int q = 0; q < 8; q++) {
        float s = 0.f;
        #pragma unroll
        for (int i = 0; i < 8; i++) {
            float e = __expf(acc[i][q] - cmax[q]);
            acc[i][q] = e; s += e;
        }
        ps[q] = s;
    }
    *(float4*)&red[tm][tt * 4]       = make_float4(ps[0], ps[1], ps[2], ps[3]);
    *(float4*)&red[tm][128 + tt * 4] = make_float4(ps[4], ps[5], ps[6], ps[7]);
    __syncthreads();
    float csum[8];
    #pragma unroll
    for (int q = 0; q < 8; q++) csum[q] = 0.f;
    #pragma unroll
    for (int tr = 0; tr < 8; tr++) {
        float4 r0 = *(const float4*)&red[tr][tt * 4];
        float4 r1 = *(const float4*)&red[tr][128 + tt * 4];
        csum[0] += r0.x; csum[1] += r0.y; csum[2] += r0.z; csum[3] += r0.w;
        csum[4] += r1.x; csum[5] += r1.y; csum[6] += r1.z; csum[7] += r1.w;
    }
    __syncthreads();

    float rinv[8];
    #pragma unroll
    for (int q = 0; q < 8; q++) rinv[q] = 1.f / csum[q];

    float msum[8];
    #pragma unroll
    for (int i = 0; i < 8; i++) msum[i] = 0.f;
    float* asnT = ws + OFF_ASNT + ((size_t)b * NP + n0) * MM;
    #pragma unroll
    for (int q = 0; q < 8; q++) {
        int col = (q < 4) ? (tt * 4 + q) : (128 + tt * 4 + (q - 4));
        float v0 = acc[0][q] * rinv[q], v1 = acc[1][q] * rinv[q];
        float v2 = acc[2][q] * rinv[q], v3 = acc[3][q] * rinv[q];
        float v4 = acc[4][q] * rinv[q], v5 = acc[5][q] * rinv[q];
        float v6 = acc[6][q] * rinv[q], v7 = acc[7][q] * rinv[q];
        msum[0] += v0; msum[1] += v1; msum[2] += v2; msum[3] += v3;
        msum[4] += v4; msum[5] += v5; msum[6] += v6; msum[7] += v7;
        *(float4*)&asnT[(size_t)col * MM + tm * 8]     = make_float4(v0, v1, v2, v3);
        *(float4*)&asnT[(size_t)col * MM + tm * 8 + 4] = make_float4(v4, v5, v6, v7);
    }
    // asum: reduce msum over tt via LDS, then atomic per m
    float* redA = &red[0][0];   // [32][64]
    *(float4*)&redA[tt * 64 + tm * 8]     = make_float4(msum[0], msum[1], msum[2], msum[3]);
    *(float4*)&redA[tt * 64 + tm * 8 + 4] = make_float4(msum[4], msum[5], msum[6], msum[7]);
    __syncthreads();
    if (t < 64) {
        float s = 0.f;
        #pragma unroll
        for (int tr = 0; tr < 32; tr++) s += redA[tr * 64 + t];
        atomicAdd(&ws[OFF_ASUM + b * MM + t], s);
    }
}

// ---------------- K4: AV = assignment @ values ----------------
__global__ __launch_bounds__(256) void k4_av(
    const float* __restrict__ values, float* __restrict__ ws)
{
    __shared__ float Vs[32][256];
    __shared__ float Ast[32][72];
    int t = threadIdx.x;
    int chunk = blockIdx.x, b = blockIdx.y;
    int tm = t >> 5, tt = t & 31;
    const float* asnT = ws + OFF_ASNT + (size_t)b * NP * MM;
    const float* vb = values + (size_t)b * NP * DD;

    float acc[8][8];
    #pragma unroll
    for (int i = 0; i < 8; i++)
        #pragma unroll
        for (int q = 0; q < 8; q++) acc[i][q] = 0.f;

    int nbase0 = chunk * 512;
    for (int kc = 0; kc < 16; kc++) {
        int nb = nbase0 + kc * 32;
        __syncthreads();
        #pragma unroll
        for (int i = 0; i < 8; i++) {
            int f = i * 256 + t;
            int kd = f >> 6, c4 = (f & 63) * 4;
            *(float4*)&Vs[kd][c4] = *(const float4*)&vb[(size_t)(nb + kd) * DD + c4];
        }
        {
            int kd = t >> 3, me = (t & 7) * 8;
            *(float4*)&Ast[kd][me]     = *(const float4*)&asnT[(size_t)(nb + kd) * MM + me];
            *(float4*)&Ast[kd][me + 4] = *(const float4*)&asnT[(size_t)(nb + kd) * MM + me + 4];
        }
        __syncthreads();
        #pragma unroll
        for (int kd = 0; kd < 32; kd++) {
            float4 a0 = *(const float4*)&Ast[kd][tm * 8];
            float4 a1 = *(const float4*)&Ast[kd][tm * 8 + 4];
            float4 b0 = *(const float4*)&Vs[kd][tt * 4];
            float4 b1 = *(const float4*)&Vs[kd][128 + tt * 4];
            float av[8] = {a0.x, a0.y, a0.z, a0.w, a1.x, a1.y, a1.z, a1.w};
            float bq[8] = {b0.x, b0.y, b0.z, b0.w, b1.x, b1.y, b1.z, b1.w};
            #pragma unroll
            for (int i = 0; i < 8; i++)
                #pragma unroll
                for (int q = 0; q < 8; q++) acc[i][q] += av[i] * bq[q];
        }
    }
    float* AV = ws + OFF_AV + (size_t)b * MM * DD;
    #pragma unroll
    for (int i = 0; i < 8; i++) {
        int m = tm * 8 + i;
        #pragma unroll
        for (int q = 0; q < 8; q++) {
            int d = (q < 4) ? (tt * 4 + q) : (128 + tt * 4 + (q - 4));
            atomicAdd(&AV[(size_t)m * DD + d], acc[i][q]);
        }
    }
}

// ---------------- K5: agg = (vc + AV) / (asum + EPS) ----------------
__global__ __launch_bounds__(256) void k5_agg(float* __restrict__ ws)
{
    int bm = blockIdx.x, t = threadIdx.x;
    float r = 1.f / (ws[OFF_ASUM + bm] + EPSF);
    size_t o = (size_t)bm * DD + t;
    ws[OFF_AGG + o] = (ws[OFF_VC + o] + ws[OFF_AV + o]) * r;
}

// ---------------- K6: x = agg^T @ assignment ----------------
__global__ __launch_bounds__(256) void k6_x(
    float* __restrict__ out, const float* __restrict__ ws)
{
    __shared__ float aggs[64][136];
    __shared__ float asns[64][136];
    int t = threadIdx.x;
    int n0 = blockIdx.x * 128, d0 = blockIdx.y * 128, b = blockIdx.z;
    const float* agg = ws + OFF_AGG + (size_t)b * MM * DD;
    const float* asnT = ws + OFF_ASNT + (size_t)b * NP * MM;

    #pragma unroll
    for (int i = 0; i < 8; i++) {
        int f = i * 256 + t;
        int m = f >> 5, c4 = (f & 31) * 4;
        *(float4*)&aggs[m][c4] = *(const float4*)&agg[(size_t)m * DD + d0 + c4];
    }
    #pragma unroll
    for (int s = 0; s < 8; s++) {
        int f = s * 256 + t;
        int nr = f >> 4, fm = f & 15;
        float4 v = *(const float4*)&asnT[(size_t)(n0 + nr) * MM + fm * 4];
        asns[fm * 4 + 0][nr] = v.x; asns[fm * 4 + 1][nr] = v.y;
        asns[fm * 4 + 2][nr] = v.z; asns[fm * 4 + 3][nr] = v.w;
    }
    __syncthreads();

    int td = t >> 4, tn = t & 15;
    float acc[8][8];
    #pragma unroll
    for (int i = 0; i < 8; i++)
        #pragma unroll
        for (int q = 0; q < 8; q++) acc[i][q] = 0.f;

    #pragma unroll 4
    for (int m = 0; m < 64; m++) {
        float4 a0 = *(const float4*)&aggs[m][td * 4];
        float4 a1 = *(const float4*)&aggs[m][64 + td * 4];
        float4 b0 = *(const float4*)&asns[m][tn * 4];
        float4 b1 = *(const float4*)&asns[m][64 + tn * 4];
        float av[8] = {a0.x, a0.y, a0.z, a0.w, a1.x, a1.y, a1.z, a1.w};
        float bq[8] = {b0.x, b0.y, b0.z, b0.w, b1.x, b1.y, b1.z, b1.w};
        #pragma unroll
        for (int i = 0; i < 8; i++)
            #pragma unroll
            for (int q = 0; q < 8; q++) acc[i][q] += av[i] * bq[q];
    }

    float* ob = out + (size_t)b * DD * NP;
    #pragma unroll
    for (int i = 0; i < 8; i++) {
        int d = d0 + ((i < 4) ? (td * 4 + i) : (64 + td * 4 + (i - 4)));
        float4 w0 = make_float4(acc[i][0], acc[i][1], acc[i][2], acc[i][3]);
        float4 w1 = make_float4(acc[i][4], acc[i][5], acc[i][6], acc[i][7]);
        *(float4*)&ob[(size_t)d * NP + n0 + tn * 4]      = w0;
        *(float4*)&ob[(size_t)d * NP + n0 + 64 + tn * 4] = w1;
    }
}

extern "C" void kernel_launch(void* const* d_in, const int* in_sizes, int n_in,
                              void* d_out, int out_size, void* d_ws, size_t ws_size,
                              hipStream_t stream) {
    const float* points    = (const float*)d_in[0];
    const float* clusters  = (const float*)d_in[1];
    const float* values    = (const float*)d_in[2];
    const float* vclusters = (const float*)d_in[3];
    const float* alpha     = (const float*)d_in[4];
    const float* beta      = (const float*)d_in[5];
    const float* cbias     = (const float*)d_in[6];
    const float* Wc        = (const float*)d_in[7];
    const float* bc        = (const float*)d_in[8];
    const float* vcbias    = (const float*)d_in[9];
    const float* Wv        = (const float*)d_in[10];
    const float* bvv       = (const float*)d_in[11];
    float* out = (float*)d_out;
    float* ws = (float*)d_ws;

    // zero AV (+agg, harmless) + asum region: floats [262144, 524800)
    hipMemsetAsync((char*)d_ws + 262144u * 4, 0, (524800u - 262144u) * 4, stream);

    k0_transpose<<<dim3(8, 8, 2), 256, 0, stream>>>(Wc, Wv, ws);
    k1_prep<<<dim3(4, 8, 2), 256, 0, stream>>>(clusters, vclusters, alpha, cbias, bc, vcbias, bvv, ws);
    k3_sim<<<dim3(64, 8), 256, 0, stream>>>(points, beta, ws);
    k4_av<<<dim3(32, 8), 256, 0, stream>>>(values, ws);
    k5_agg<<<dim3(512), 256, 0, stream>>>(ws);
    k6_x<<<dim3(128, 2, 8), 256, 0, stream>>>(out, ws);
}

// Round 2
// 479.697 us; speedup vs baseline: 1.1267x; 1.1267x over previous
//
#include <hip/hip_runtime.h>
#include <math.h>

#define BB 8
#define MM 64
#define DD 256
#define NP 16384
#define EPSF 1e-7f
#define NEPS 1e-12f

// ws layout (float offsets)
#define OFF_AT   0u          // At   [B][D][M]  alpha * normalized c, transposed
#define OFF_VC   131072u     // vc   [B][M][D]
#define OFF_AGG  262144u     // agg  [B][M][D]
#define OFF_ASUM 393216u     // asum [B][M]
#define OFF_ASNT 393728u     // asnT [B][N][M]  assignment transposed
#define OFF_WCT  8782336u    // Wc^T [D][D]
#define OFF_WVT  8847872u    // Wv^T [D][D]
#define OFF_PART 8913408u    // part [64][B][M][D] split-K partials (32 MB)

// ---------------- K0: transpose Wc, Wv ----------------
__global__ __launch_bounds__(256) void k0_transpose(
    const float* __restrict__ Wc, const float* __restrict__ Wv,
    float* __restrict__ ws)
{
    __shared__ float tls[32][33];
    int which = blockIdx.z;
    const float* W = which ? Wv : Wc;
    float* Wt = ws + (which ? OFF_WVT : OFF_WCT);
    int j0 = blockIdx.x * 32, k0 = blockIdx.y * 32;
    int c = threadIdx.x & 31, r0 = threadIdx.x >> 5;
    #pragma unroll
    for (int rr = r0; rr < 32; rr += 8)
        tls[rr][c] = W[(size_t)(j0 + rr) * DD + k0 + c];
    __syncthreads();
    #pragma unroll
    for (int rr = r0; rr < 32; rr += 8)
        Wt[(size_t)(k0 + rr) * DD + j0 + c] = tls[c][rr];
}

// ---------------- K1: c / vc prep ----------------
__global__ __launch_bounds__(256) void k1_prep(
    const float* __restrict__ clusters, const float* __restrict__ vclusters,
    const float* __restrict__ alpha, const float* __restrict__ cbias,
    const float* __restrict__ bc, const float* __restrict__ vcbias,
    const float* __restrict__ bvv, float* __restrict__ ws)
{
    __shared__ float s_in[16][256];
    __shared__ float wt_s[32][256];
    __shared__ float s_out[16][260];
    __shared__ float s_scale[16];

    int t = threadIdx.x;
    int mt = blockIdx.x, b = blockIdx.y, which = blockIdx.z;
    int m0 = mt * 16;
    const float* inp   = which ? vclusters : clusters;
    const float* ibias = which ? vcbias : cbias;
    const float* obias = which ? bvv : bc;
    const float* Wt = ws + (which ? OFF_WVT : OFF_WCT);

    #pragma unroll
    for (int i = 0; i < 4; i++) {
        int e = i * 1024 + t * 4;
        int r = e >> 8, c = e & 255;
        float4 a  = *(const float4*)&inp[((size_t)(b * MM + m0 + r)) * DD + c];
        float4 bb = *(const float4*)&ibias[(size_t)(m0 + r) * DD + c];
        a.x += bb.x; a.y += bb.y; a.z += bb.z; a.w += bb.w;
        *(float4*)&s_in[r][c] = a;
    }

    int tm = t >> 5, tt = t & 31;
    float acc[2][8];
    #pragma unroll
    for (int i = 0; i < 2; i++)
        #pragma unroll
        for (int q = 0; q < 8; q++) acc[i][q] = 0.f;

    for (int k0 = 0; k0 < DD; k0 += 32) {
        __syncthreads();
        #pragma unroll
        for (int i = 0; i < 8; i++) {
            int e = i * 1024 + t * 4;
            int kd = e >> 8, c = e & 255;
            *(float4*)&wt_s[kd][c] = *(const float4*)&Wt[(size_t)(k0 + kd) * DD + c];
        }
        __syncthreads();
        #pragma unroll
        for (int kd = 0; kd < 32; kd++) {
            float a0 = s_in[tm][k0 + kd];
            float a1 = s_in[tm + 8][k0 + kd];
            float4 b0 = *(const float4*)&wt_s[kd][tt * 4];
            float4 b1 = *(const float4*)&wt_s[kd][128 + tt * 4];
            float bq[8] = {b0.x, b0.y, b0.z, b0.w, b1.x, b1.y, b1.z, b1.w};
            #pragma unroll
            for (int q = 0; q < 8; q++) { acc[0][q] += a0 * bq[q]; acc[1][q] += a1 * bq[q]; }
        }
    }

    #pragma unroll
    for (int q = 0; q < 8; q++) {
        int col = (q < 4) ? (tt * 4 + q) : (128 + tt * 4 + (q - 4));
        float ob = obias[col];
        #pragma unroll
        for (int i = 0; i < 2; i++) {
            int r = tm + i * 8;
            float x = acc[i][q] + ob;
            float s = x / (1.f + __expf(-x));   // silu
            s_out[r][col] = s;
        }
    }
    __syncthreads();

    if (which == 0) {
        if (t < 16) {
            float ss = 0.f;
            for (int j = 0; j < 256; j++) { float v = s_out[t][j]; ss += v * v; }
            s_scale[t] = alpha[m0 + t] / fmaxf(sqrtf(ss), NEPS);
        }
        __syncthreads();
        float* At = ws + OFF_AT + (size_t)b * DD * MM + (size_t)t * MM + m0;
        #pragma unroll
        for (int i = 0; i < 16; i++) At[i] = s_out[i][t] * s_scale[i];
    } else {
        float* vc = ws + OFF_VC + (size_t)(b * MM + m0) * DD;
        #pragma unroll
        for (int i = 0; i < 16; i++) vc[(size_t)i * DD + t] = s_out[i][t];
    }
}

// ---------------- K3: sim + softmax + asnT + asum ----------------
// 512 threads, grid (64,8): tile 64m x 256n, micro 8m x 4n
__global__ __launch_bounds__(512, 4) void k3_sim(
    const float* __restrict__ points, const float* __restrict__ beta,
    float* __restrict__ ws)
{
    __shared__ float Ps[32][256];     // 32 KB
    __shared__ float Ast[32][72];     // 9 KB
    __shared__ float pinv_s[256];     // 1 KB
    __shared__ float red[8][256];     // 8 KB

    int t = threadIdx.x;
    int n0 = blockIdx.x * 256, b = blockIdx.y;
    int tm = t >> 6, tt = t & 63;     // tm: wave id (m-group), tt: lane (n-group)
    const float* At = ws + OFF_AT + (size_t)b * DD * MM;
    const float* pb = points + (size_t)b * DD * NP;

    float acc[8][4];
    #pragma unroll
    for (int i = 0; i < 8; i++)
        #pragma unroll
        for (int q = 0; q < 4; q++) acc[i][q] = 0.f;

    float sq[4] = {0.f, 0.f, 0.f, 0.f};
    int srow = t >> 6, scol = (t & 63) * 4;

    for (int k0c = 0; k0c < DD; k0c += 32) {
        __syncthreads();
        #pragma unroll
        for (int i = 0; i < 4; i++) {
            int row = i * 8 + srow;
            float4 v = *(const float4*)&pb[(size_t)(k0c + row) * NP + n0 + scol];
            sq[0] += v.x * v.x; sq[1] += v.y * v.y;
            sq[2] += v.z * v.z; sq[3] += v.w * v.w;
            *(float4*)&Ps[row][scol] = v;
        }
        {
            int kd = t >> 4, me4 = (t & 15) * 4;
            *(float4*)&Ast[kd][me4] = *(const float4*)&At[(size_t)(k0c + kd) * MM + me4];
        }
        __syncthreads();
        #pragma unroll
        for (int kd = 0; kd < 32; kd++) {
            float4 a0 = *(const float4*)&Ast[kd][tm * 8];
            float4 a1 = *(const float4*)&Ast[kd][tm * 8 + 4];
            float4 b0 = *(const float4*)&Ps[kd][tt * 4];
            float av[8] = {a0.x, a0.y, a0.z, a0.w, a1.x, a1.y, a1.z, a1.w};
            float bq[4] = {b0.x, b0.y, b0.z, b0.w};
            #pragma unroll
            for (int i = 0; i < 8; i++)
                #pragma unroll
                for (int q = 0; q < 4; q++) acc[i][q] += av[i] * bq[q];
        }
    }

    // column sumsq -> pinv
    __syncthreads();
    *(float4*)&red[srow][scol] = make_float4(sq[0], sq[1], sq[2], sq[3]);
    __syncthreads();
    if (t < 256) {
        float s = 0.f;
        #pragma unroll
        for (int r = 0; r < 8; r++) s += red[r][t];
        pinv_s[t] = 1.f / fmaxf(sqrtf(s), NEPS);
    }
    __syncthreads();

    float pin[4];
    { float4 p4 = *(const float4*)&pinv_s[tt * 4];
      pin[0] = p4.x; pin[1] = p4.y; pin[2] = p4.z; pin[3] = p4.w; }
    float sbet[8];
    #pragma unroll
    for (int i = 0; i < 8; i++) sbet[i] = beta[tm * 8 + i];

    float pmax[4] = {-1e30f, -1e30f, -1e30f, -1e30f};
    #pragma unroll
    for (int q = 0; q < 4; q++)
        #pragma unroll
        for (int i = 0; i < 8; i++) {
            acc[i][q] = acc[i][q] * pin[q] + sbet[i];
            pmax[q] = fmaxf(pmax[q], acc[i][q]);
        }
    *(float4*)&red[tm][tt * 4] = make_float4(pmax[0], pmax[1], pmax[2], pmax[3]);
    __syncthreads();
    float cmax[4] = {-1e30f, -1e30f, -1e30f, -1e30f};
    #pragma unroll
    for (int r = 0; r < 8; r++) {
        float4 rr = *(const float4*)&red[r][tt * 4];
        cmax[0] = fmaxf(cmax[0], rr.x); cmax[1] = fmaxf(cmax[1], rr.y);
        cmax[2] = fmaxf(cmax[2], rr.z); cmax[3] = fmaxf(cmax[3], rr.w);
    }
    __syncthreads();
    float ps[4] = {0.f, 0.f, 0.f, 0.f};
    #pragma unroll
    for (int q = 0; q < 4; q++)
        #pragma unroll
        for (int i = 0; i < 8; i++) {
            float e = __expf(acc[i][q] - cmax[q]);
            acc[i][q] = e; ps[q] += e;
        }
    *(float4*)&red[tm][tt * 4] = make_float4(ps[0], ps[1], ps[2], ps[3]);
    __syncthreads();
    float csum[4] = {0.f, 0.f, 0.f, 0.f};
    #pragma unroll
    for (int r = 0; r < 8; r++) {
        float4 rr = *(const float4*)&red[r][tt * 4];
        csum[0] += rr.x; csum[1] += rr.y; csum[2] += rr.z; csum[3] += rr.w;
    }

    float rinv[4];
    #pragma unroll
    for (int q = 0; q < 4; q++) rinv[q] = 1.f / csum[q];

    float msum[8];
    #pragma unroll
    for (int i = 0; i < 8; i++) msum[i] = 0.f;
    float* asnT = ws + OFF_ASNT + ((size_t)b * NP + n0) * MM;
    #pragma unroll
    for (int q = 0; q < 4; q++) {
        size_t col = (size_t)(tt * 4 + q);
        float v0 = acc[0][q] * rinv[q], v1 = acc[1][q] * rinv[q];
        float v2 = acc[2][q] * rinv[q], v3 = acc[3][q] * rinv[q];
        float v4 = acc[4][q] * rinv[q], v5 = acc[5][q] * rinv[q];
        float v6 = acc[6][q] * rinv[q], v7 = acc[7][q] * rinv[q];
        msum[0] += v0; msum[1] += v1; msum[2] += v2; msum[3] += v3;
        msum[4] += v4; msum[5] += v5; msum[6] += v6; msum[7] += v7;
        *(float4*)&asnT[col * MM + tm * 8]     = make_float4(v0, v1, v2, v3);
        *(float4*)&asnT[col * MM + tm * 8 + 4] = make_float4(v4, v5, v6, v7);
    }
    // asum: wave shuffle reduce (lanes = n), lane 0 atomics
    #pragma unroll
    for (int i = 0; i < 8; i++) {
        #pragma unroll
        for (int off = 32; off > 0; off >>= 1)
            msum[i] += __shfl_xor(msum[i], off);
    }
    if ((t & 63) == 0) {
        #pragma unroll
        for (int i = 0; i < 8; i++)
            atomicAdd(&ws[OFF_ASUM + b * MM + tm * 8 + i], msum[i]);
    }
}

// ---------------- K4: split-K partials of assignment @ values ----------------
// 512 threads, grid (64,8): slice = 256 n's; micro 8m x 4d
__global__ __launch_bounds__(512, 4) void k4_av(
    const float* __restrict__ values, float* __restrict__ ws)
{
    __shared__ float Vs[16][256];    // 16 KB
    __shared__ float Ast[16][72];    // 4.5 KB
    int t = threadIdx.x;
    int slice = blockIdx.x, b = blockIdx.y;
    int tm = t >> 6, tt = t & 63;
    const float* asnT = ws + OFF_ASNT + (size_t)b * NP * MM;
    const float* vb = values + (size_t)b * NP * DD;

    float acc[8][4];
    #pragma unroll
    for (int i = 0; i < 8; i++)
        #pragma unroll
        for (int q = 0; q < 4; q++) acc[i][q] = 0.f;

    int nbase = slice * 256;
    for (int kc = 0; kc < 16; kc++) {
        int nb = nbase + kc * 16;
        __syncthreads();
        #pragma unroll
        for (int i = 0; i < 2; i++) {
            int f = i * 512 + t;
            int kd = f >> 6, c4 = (f & 63) * 4;
            *(float4*)&Vs[kd][c4] = *(const float4*)&vb[(size_t)(nb + kd) * DD + c4];
        }
        if (t < 256) {
            int kd = t >> 4, me4 = (t & 15) * 4;
            *(float4*)&Ast[kd][me4] = *(const float4*)&asnT[(size_t)(nb + kd) * MM + me4];
        }
        __syncthreads();
        #pragma unroll
        for (int kd = 0; kd < 16; kd++) {
            float4 a0 = *(const float4*)&Ast[kd][tm * 8];
            float4 a1 = *(const float4*)&Ast[kd][tm * 8 + 4];
            float4 b0 = *(const float4*)&Vs[kd][tt * 4];
            float av[8] = {a0.x, a0.y, a0.z, a0.w, a1.x, a1.y, a1.z, a1.w};
            float bq[4] = {b0.x, b0.y, b0.z, b0.w};
            #pragma unroll
            for (int i = 0; i < 8; i++)
                #pragma unroll
                for (int q = 0; q < 4; q++) acc[i][q] += av[i] * bq[q];
        }
    }
    float* part = ws + OFF_PART + ((size_t)slice * BB + b) * MM * DD;
    #pragma unroll
    for (int i = 0; i < 8; i++) {
        int m = tm * 8 + i;
        *(float4*)&part[(size_t)m * DD + tt * 4] =
            make_float4(acc[i][0], acc[i][1], acc[i][2], acc[i][3]);
    }
}

// ---------------- K5: agg = (vc + sum_s part) / (asum + EPS) ----------------
__global__ __launch_bounds__(256) void k5_agg(float* __restrict__ ws)
{
    int bm = blockIdx.x, t = threadIdx.x;
    float r = 1.f / (ws[OFF_ASUM + bm] + EPSF);
    size_t o = (size_t)bm * DD + t;
    const float* part = ws + OFF_PART;
    float s0 = 0.f, s1 = 0.f, s2 = 0.f, s3 = 0.f;
    #pragma unroll 4
    for (int s = 0; s < 64; s += 4) {
        s0 += part[(size_t)(s + 0) * (BB * MM * DD) + o];
        s1 += part[(size_t)(s + 1) * (BB * MM * DD) + o];
        s2 += part[(size_t)(s + 2) * (BB * MM * DD) + o];
        s3 += part[(size_t)(s + 3) * (BB * MM * DD) + o];
    }
    ws[OFF_AGG + o] = (ws[OFF_VC + o] + ((s0 + s1) + (s2 + s3))) * r;
}

// ---------------- K6: x = agg^T @ assignment ----------------
// 256 threads, grid (128,4,8): tile 64d x 128n, micro 8d x 4n
__global__ __launch_bounds__(256, 3) void k6_x(
    float* __restrict__ out, const float* __restrict__ ws)
{
    __shared__ float aggs[64][68];    // 17 KB  [m][d-tile]
    __shared__ float asns[64][132];   // 33 KB  [m][n-tile]
    int t = threadIdx.x;
    int n0 = blockIdx.x * 128, d0 = blockIdx.y * 64, b = blockIdx.z;
    const float* agg = ws + OFF_AGG + (size_t)b * MM * DD;
    const float* asnT = ws + OFF_ASNT + (size_t)b * NP * MM;

    #pragma unroll
    for (int i = 0; i < 4; i++) {
        int f = i * 256 + t;
        int m = f >> 4, c4 = (f & 15) * 4;
        *(float4*)&aggs[m][c4] = *(const float4*)&agg[(size_t)m * DD + d0 + c4];
    }
    #pragma unroll
    for (int s = 0; s < 8; s++) {
        int f = s * 256 + t;
        int nr = f >> 4, fm = f & 15;
        float4 v = *(const float4*)&asnT[(size_t)(n0 + nr) * MM + fm * 4];
        asns[fm * 4 + 0][nr] = v.x; asns[fm * 4 + 1][nr] = v.y;
        asns[fm * 4 + 2][nr] = v.z; asns[fm * 4 + 3][nr] = v.w;
    }
    __syncthreads();

    int td = t >> 5, tn = t & 31;
    float acc[8][4];
    #pragma unroll
    for (int i = 0; i < 8; i++)
        #pragma unroll
        for (int q = 0; q < 4; q++) acc[i][q] = 0.f;

    #pragma unroll 8
    for (int m = 0; m < 64; m++) {
        float4 a0 = *(const float4*)&aggs[m][td * 4];
        float4 a1 = *(const float4*)&aggs[m][32 + td * 4];
        float4 b0 = *(const float4*)&asns[m][tn * 4];
        float av[8] = {a0.x, a0.y, a0.z, a0.w, a1.x, a1.y, a1.z, a1.w};
        float bq[4] = {b0.x, b0.y, b0.z, b0.w};
        #pragma unroll
        for (int i = 0; i < 8; i++)
            #pragma unroll
            for (int q = 0; q < 4; q++) acc[i][q] += av[i] * bq[q];
    }

    float* ob = out + (size_t)b * DD * NP;
    #pragma unroll
    for (int i = 0; i < 8; i++) {
        int d = d0 + ((i < 4) ? (td * 4 + i) : (32 + td * 4 + (i - 4)));
        *(float4*)&ob[(size_t)d * NP + n0 + tn * 4] =
            make_float4(acc[i][0], acc[i][1], acc[i][2], acc[i][3]);
    }
}

extern "C" void kernel_launch(void* const* d_in, const int* in_sizes, int n_in,
                              void* d_out, int out_size, void* d_ws, size_t ws_size,
                              hipStream_t stream) {
    const float* points    = (const float*)d_in[0];
    const float* clusters  = (const float*)d_in[1];
    const float* values    = (const float*)d_in[2];
    const float* vclusters = (const float*)d_in[3];
    const float* alpha     = (const float*)d_in[4];
    const float* beta      = (const float*)d_in[5];
    const float* cbias     = (const float*)d_in[6];
    const float* Wc        = (const float*)d_in[7];
    const float* bc        = (const float*)d_in[8];
    const float* vcbias    = (const float*)d_in[9];
    const float* Wv        = (const float*)d_in[10];
    const float* bvv       = (const float*)d_in[11];
    float* out = (float*)d_out;
    float* ws = (float*)d_ws;

    // zero asum only (partials are fully overwritten, agg written by k5)
    hipMemsetAsync((char*)d_ws + (size_t)OFF_ASUM * 4, 0, 512 * 4, stream);

    k0_transpose<<<dim3(8, 8, 2), 256, 0, stream>>>(Wc, Wv, ws);
    k1_prep<<<dim3(4, 8, 2), 256, 0, stream>>>(clusters, vclusters, alpha, cbias, bc, vcbias, bvv, ws);
    k3_sim<<<dim3(64, 8), 512, 0, stream>>>(points, beta, ws);
    k4_av<<<dim3(64, 8), 512, 0, stream>>>(values, ws);
    k5_agg<<<dim3(512), 256, 0, stream>>>(ws);
    k6_x<<<dim3(128, 4, 8), 256, 0, stream>>>(out, ws);
}